// Round 1
// 498.614 us; speedup vs baseline: 1.0544x; 1.0544x over previous
//
#include <hip/hip_runtime.h>
#include <cstdint>
#include <cstddef>

#define NOBJ 32
#define NP   992
#define DD   256
#define SP   196   // 14*14
#define OC   151
#define RC   51
#define RED  64
#define KIN  4251  // 4096 + 151 + 4
#define CH   128   // emb1 k-chunks
#define KPC  34    // ceil(4251/128)

// ---- ws layout (float offsets) ----
#define OFF_PART   0u         // 128*32*256 = 1048576
#define OFF_OBJF   1048576u   // 8192
#define OFF_SALL   1056768u   // 992*768 = 761856
#define OFF_RELF   1818624u   // 253952
#define OFF_H      2072576u   // 262144
#define OFF_W2T    2334720u   // 65536
#define OFF_WC1T   2400256u   // 196608
#define OFF_WC2T   2596864u   // 65536
#define OFF_WGT    2662400u   // 65536
#define OFF_FC1WT  2727936u   // 49152
#define OFF_FC2WT  2777088u   // 49152
#define OFF_WOPT   2826240u   // 38656
#define OFF_WRPT   2864896u   // 13056

#define TR_TOT 543232  // total transposed elements

#define TCH  32        // channels per union tile
#define NTIL 8         // 256 / TCH
#define TF4  1568      // TCH*SP/4 float4 per tile

// ============ K_PRE: union(0..991) + emb1(992..1119) + transpose(1120..1375)
__global__ void __launch_bounds__(256, 5)
k_pre(const float* __restrict__ uf,
      const float* __restrict__ bbox,
      const int* __restrict__ pairs,
      const float* __restrict__ roi,
      const float* __restrict__ logits,
      const float* __restrict__ W1,
      const float* __restrict__ W2,  const float* __restrict__ Wc1,
      const float* __restrict__ Wc2, const float* __restrict__ Wg,
      const float* __restrict__ f1w, const float* __restrict__ f2w,
      const float* __restrict__ Wop, const float* __restrict__ Wrp,
      float* __restrict__ sAll, float* __restrict__ part,
      float* __restrict__ W2T,  float* __restrict__ Wc1T,
      float* __restrict__ Wc2T, float* __restrict__ WgT,
      float* __restrict__ f1wT, float* __restrict__ f2wT,
      float* __restrict__ WopT, float* __restrict__ WrpT) {
  const int b = blockIdx.x, t = threadIdx.x;
  if (b < NP) {
    // ---- union masked means: 32-ch tiles, reg-staged prefetch, shfl reduce
    const int p = b;
    __shared__ __align__(16) float buf[TCH * SP + 28];  // 25200 B (+28f slack)
    __shared__ __align__(16) float mS[224];             // masks padded to 224
    __shared__ __align__(16) float mO[224];
    __shared__ __align__(16) float mB[224];
    if (t < 224) {
      float sm = 0.f, om = 0.f, bm = 0.f;
      if (t < SP) {
        int si = pairs[2 * p], oi = pairs[2 * p + 1];
        float sx1 = bbox[si * 4 + 0], sy1 = bbox[si * 4 + 1];
        float sx2 = bbox[si * 4 + 2], sy2 = bbox[si * 4 + 3];
        float ox1 = bbox[oi * 4 + 0], oy1 = bbox[oi * 4 + 1];
        float ox2 = bbox[oi * 4 + 2], oy2 = bbox[oi * 4 + 3];
        float ux = fminf(sx1, ox1), uy = fminf(sy1, oy1);
        float xr = 14.f / fmaxf(sx2 - ux, ox2 - ux);
        float yr = 14.f / fmaxf(sy2 - uy, oy2 - uy);
        float xs0 = rintf((sx1 - ux) * xr), xs1 = rintf((sx2 - ux) * xr);
        float xo0 = rintf((ox1 - ux) * xr), xo1 = rintf((ox2 - ux) * xr);
        float ys0 = rintf((sy1 - uy) * yr), ys1 = rintf((sy2 - uy) * yr);
        float yo0 = rintf((oy1 - uy) * yr), yo1 = rintf((oy2 - uy) * yr);
        int a = t / 14, bb = t - a * 14;
        float fa = (float)a, fb = (float)bb;
        sm = (fa >= xs0 && fa < xs1 && fb >= ys0 && fb < ys1) ? 1.f : 0.f;
        om = (fa >= xo0 && fa < xo1 && fb >= yo0 && fb < yo1) ? 1.f : 0.f;
        bm = fminf(fmaxf(1.f - sm - om, 0.f), 1.f);
      }
      mS[t] = sm; mO[t] = om; mB[t] = bm;
    }
    if (t < 28) buf[TCH * SP + t] = 0.f;   // zero slack (slice 7 of ch 31 reads it)
    // prologue: tile 0 direct copy (coalesced)
    const float4* base4 = (const float4*)(uf + (size_t)p * (DD * SP));
    {
      const float4* src = base4 + t;
      float4* dst = (float4*)buf + t;
      dst[0] = src[0];     dst[256] = src[256];   dst[512] = src[512];
      dst[768] = src[768]; dst[1024] = src[1024]; dst[1280] = src[1280];
      if (t < 32) dst[1536] = src[1536];
    }
    __syncthreads();
    const int cl = t >> 3, o = t & 7;          // channel-in-tile, 28-float slice
    const float* row = buf + cl * SP + o * 28; // 16B-aligned (784/112-byte steps)
    const float* msp = mS + o * 28;
    const float* mop = mO + o * 28;
    const float* mbp = mB + o * 28;
    const float inv = 1.f / 196.f;
    float4 s0, s1, s2, s3, s4, s5, s6 = {0.f, 0.f, 0.f, 0.f};
#pragma unroll 1
    for (int ti = 0; ti < NTIL; ++ti) {
      // issue next-tile loads early (coalesced); ds_write happens after barrier,
      // so HBM latency hides under this tile's compute (T14 async-STAGE split)
      if (ti < NTIL - 1) {
        const float4* src = base4 + (ti + 1) * TF4 + t;
        s0 = src[0];     s1 = src[256];   s2 = src[512];
        s3 = src[768];   s4 = src[1024];  s5 = src[1280];
        if (t < 32) s6 = src[1536];
      }
      float aS = 0.f, aO = 0.f, aB = 0.f;
#pragma unroll
      for (int j = 0; j < 7; ++j) {
        float4 v = *(const float4*)&row[4 * j];
        float4 x = *(const float4*)&msp[4 * j];
        float4 y = *(const float4*)&mop[4 * j];
        float4 z = *(const float4*)&mbp[4 * j];
        aS += v.x * x.x + v.y * x.y + v.z * x.z + v.w * x.w;
        aO += v.x * y.x + v.y * y.y + v.z * y.z + v.w * y.w;
        aB += v.x * z.x + v.y * z.y + v.z * z.z + v.w * z.w;
      }
      // butterfly over the 8 slice-lanes of each channel
      aS += __shfl_xor(aS, 1); aS += __shfl_xor(aS, 2); aS += __shfl_xor(aS, 4);
      aO += __shfl_xor(aO, 1); aO += __shfl_xor(aO, 2); aO += __shfl_xor(aO, 4);
      aB += __shfl_xor(aB, 1); aB += __shfl_xor(aB, 2); aB += __shfl_xor(aB, 4);
      const int ch = ti * TCH + cl;
      if (o == 0)      sAll[(size_t)p * 768 + ch]       = aS * inv;
      else if (o == 1) sAll[(size_t)p * 768 + 256 + ch] = aO * inv;
      else if (o == 2) sAll[(size_t)p * 768 + 512 + ch] = aB * inv;
      if (ti < NTIL - 1) {
        __syncthreads();   // all lanes done reading buf for tile ti
        float4* dst = (float4*)buf + t;
        dst[0] = s0;     dst[256] = s1;   dst[512] = s2;
        dst[768] = s3;   dst[1024] = s4;  dst[1280] = s5;
        if (t < 32) dst[1536] = s6;
        __syncthreads();   // tile ti+1 visible
      }
    }
  } else if (b < NP + CH) {
    // ---- emb1 split-K partial ----
    const int chunk = b - NP;
    int k0 = chunk * KPC;
    int k1 = k0 + KPC; if (k1 > KIN) k1 = KIN;
    float acc[NOBJ];
#pragma unroll
    for (int i = 0; i < NOBJ; ++i) acc[i] = 0.f;
#pragma unroll 2
    for (int k = k0; k < k1; ++k) {
      float w = W1[(size_t)k * DD + t];
      const float* xp; int stride;
      if (k < 4096)            { xp = roi    + k;               stride = 4096; }
      else if (k < 4096 + OC)  { xp = logits + (k - 4096);      stride = OC;   }
      else                     { xp = bbox   + (k - 4096 - OC); stride = 4;    }
#pragma unroll
      for (int i = 0; i < NOBJ; ++i) { acc[i] += xp[0] * w; xp += stride; }
    }
    float* pout = part + (size_t)chunk * (NOBJ * DD) + t;
#pragma unroll
    for (int i = 0; i < NOBJ; ++i) pout[i * DD] = acc[i];
  } else {
    // ---- weight transposes: coalesced writes, strided (L2-hit) reads ----
    for (int o = (b - NP - CH) * 256 + t; o < TR_TOT; o += 256 * 256) {
      float v; float* dst;
      if (o < 65536)       { int q = o;          v = W2 [(q & 255) * 256 + (q >> 8)]; dst = W2T  + q; }
      else if (o < 262144) { int q = o - 65536;  int c = q / 768, k = q - c * 768;
                             v = Wc1[k * 256 + c];                                    dst = Wc1T + q; }
      else if (o < 327680) { int q = o - 262144; v = Wc2[(q & 255) * 256 + (q >> 8)]; dst = Wc2T + q; }
      else if (o < 393216) { int q = o - 327680; v = Wg [(q & 255) * 256 + (q >> 8)]; dst = WgT  + q; }
      else if (o < 442368) { int q = o - 393216;
                             v = f1w[(q >> 14) * 16384 + (q & 255) * 64 + ((q >> 8) & 63)];
                             dst = f1wT + q; }
      else if (o < 491520) { int q = o - 442368;
                             v = f2w[(q >> 14) * 16384 + (q & 63) * 256 + ((q >> 6) & 255)];
                             dst = f2wT + q; }
      else if (o < 530176) { int q = o - 491520; v = Wop[(q & 255) * OC + (q >> 8)];  dst = WopT + q; }
      else                 { int q = o - 530176; v = Wrp[(q & 255) * RC + (q >> 8)];  dst = WrpT + q; }
      *dst = v;
    }
  }
}

// ============ K_MID2: attrel w/ K-split x2 + H fusion; emb2 + H fusion =====
__global__ void __launch_bounds__(512, 1)
k_mid2(const float* __restrict__ sAll,
       const float* __restrict__ f1wT, const float* __restrict__ f1b,
       const float* __restrict__ f2wT, const float* __restrict__ f2b,
       const float* __restrict__ Wc1T, const float* __restrict__ bc1,
       const float* __restrict__ Wc2T, const float* __restrict__ bc2,
       const float* __restrict__ WgT,
       const float* __restrict__ part, const float* __restrict__ b1,
       const float* __restrict__ W2T,  const float* __restrict__ b2,
       float* __restrict__ relf, float* __restrict__ objf,
       float* __restrict__ H) {
  const int b = blockIdx.x, t = threadIdx.x;
  const int h = t >> 8, tt = t & 255;
  __shared__ __align__(16) float sg[4][768];
  __shared__ __align__(16) float ha[4][192];
  __shared__ __align__(16) float h2[4][256];
  __shared__ __align__(16) float red[2][4][256];
  if (b < NP / 4) {
    const int p0 = b * 4;
    {
      const float4* src = (const float4*)(sAll + (size_t)p0 * 768);
      float4* dst = (float4*)&sg[0][0];
      for (int j = t; j < 768; j += 512) dst[j] = src[j];
    }
    __syncthreads();
    // ---- P1: fc1 (cols tt<192, K=256 split 128 by h) ----
    if (tt < 192) {
      const float4* w4 = (const float4*)(f1wT + tt * 256 + h * 128);
      const int sb = (tt >> 6) * 256 + h * 128;
      float a0 = 0, a1 = 0, a2 = 0, a3 = 0;
#pragma unroll 8
      for (int j = 0; j < 32; ++j) {
        float4 wv = w4[j];
        float4 s0 = *(const float4*)&sg[0][sb + 4 * j];
        float4 s1 = *(const float4*)&sg[1][sb + 4 * j];
        float4 s2 = *(const float4*)&sg[2][sb + 4 * j];
        float4 s3 = *(const float4*)&sg[3][sb + 4 * j];
        a0 += s0.x * wv.x + s0.y * wv.y + s0.z * wv.z + s0.w * wv.w;
        a1 += s1.x * wv.x + s1.y * wv.y + s1.z * wv.z + s1.w * wv.w;
        a2 += s2.x * wv.x + s2.y * wv.y + s2.z * wv.z + s2.w * wv.w;
        a3 += s3.x * wv.x + s3.y * wv.y + s3.z * wv.z + s3.w * wv.w;
      }
      red[h][0][tt] = a0; red[h][1][tt] = a1; red[h][2][tt] = a2; red[h][3][tt] = a3;
    }
    __syncthreads();
    if (h == 0 && tt < 192) {
      float bb = f1b[tt];
#pragma unroll
      for (int p = 0; p < 4; ++p)
        ha[p][tt] = fmaxf(red[0][p][tt] + red[1][p][tt] + bb, 0.f);
    }
    __syncthreads();
    // ---- P2: fc2 + sigmoid gate ----
    for (int br = 0; br < 3; ++br) {
      const float4* w4 = (const float4*)(f2wT + br * 16384 + tt * 64 + h * 32);
      const int hb = br * 64 + h * 32;
      float a0 = 0, a1 = 0, a2 = 0, a3 = 0;
#pragma unroll
      for (int j = 0; j < 8; ++j) {
        float4 wv = w4[j];
        float4 v0 = *(const float4*)&ha[0][hb + 4 * j];
        float4 v1 = *(const float4*)&ha[1][hb + 4 * j];
        float4 v2 = *(const float4*)&ha[2][hb + 4 * j];
        float4 v3 = *(const float4*)&ha[3][hb + 4 * j];
        a0 += v0.x * wv.x + v0.y * wv.y + v0.z * wv.z + v0.w * wv.w;
        a1 += v1.x * wv.x + v1.y * wv.y + v1.z * wv.z + v1.w * wv.w;
        a2 += v2.x * wv.x + v2.y * wv.y + v2.z * wv.z + v2.w * wv.w;
        a3 += v3.x * wv.x + v3.y * wv.y + v3.z * wv.z + v3.w * wv.w;
      }
      red[h][0][tt] = a0; red[h][1][tt] = a1; red[h][2][tt] = a2; red[h][3][tt] = a3;
      __syncthreads();
      if (h == 0) {
        float bb = f2b[br * 256 + tt];
#pragma unroll
        for (int p = 0; p < 4; ++p) {
          float g = 1.f / (1.f + expf(-(red[0][p][tt] + red[1][p][tt] + bb)));
          sg[p][br * 256 + tt] *= g;
        }
      }
      __syncthreads();
    }
    // ---- P3: rel fc1 768->256 relu ----
    {
      const float4* w4 = (const float4*)(Wc1T + (size_t)tt * 768 + h * 384);
      const int gb = h * 384;
      float a0 = 0, a1 = 0, a2 = 0, a3 = 0;
#pragma unroll 8
      for (int j = 0; j < 96; ++j) {
        float4 wv = w4[j];
        float4 g0 = *(const float4*)&sg[0][gb + 4 * j];
        float4 g1 = *(const float4*)&sg[1][gb + 4 * j];
        float4 g2 = *(const float4*)&sg[2][gb + 4 * j];
        float4 g3 = *(const float4*)&sg[3][gb + 4 * j];
        a0 += g0.x * wv.x + g0.y * wv.y + g0.z * wv.z + g0.w * wv.w;
        a1 += g1.x * wv.x + g1.y * wv.y + g1.z * wv.z + g1.w * wv.w;
        a2 += g2.x * wv.x + g2.y * wv.y + g2.z * wv.z + g2.w * wv.w;
        a3 += g3.x * wv.x + g3.y * wv.y + g3.z * wv.z + g3.w * wv.w;
      }
      red[h][0][tt] = a0; red[h][1][tt] = a1; red[h][2][tt] = a2; red[h][3][tt] = a3;
    }
    __syncthreads();
    if (h == 0) {
      float bb = bc1[tt];
#pragma unroll
      for (int p = 0; p < 4; ++p)
        h2[p][tt] = fmaxf(red[0][p][tt] + red[1][p][tt] + bb, 0.f);
    }
    __syncthreads();
    // ---- P4: rel fc2 -> relf + stash ----
    {
      const float4* w4 = (const float4*)(Wc2T + (size_t)tt * 256 + h * 128);
      const int hb = h * 128;
      float a0 = 0, a1 = 0, a2 = 0, a3 = 0;
#pragma unroll 8
      for (int j = 0; j < 32; ++j) {
        float4 wv = w4[j];
        float4 v0 = *(const float4*)&h2[0][hb + 4 * j];
        float4 v1 = *(const float4*)&h2[1][hb + 4 * j];
        float4 v2 = *(const float4*)&h2[2][hb + 4 * j];
        float4 v3 = *(const float4*)&h2[3][hb + 4 * j];
        a0 += v0.x * wv.x + v0.y * wv.y + v0.z * wv.z + v0.w * wv.w;
        a1 += v1.x * wv.x + v1.y * wv.y + v1.z * wv.z + v1.w * wv.w;
        a2 += v2.x * wv.x + v2.y * wv.y + v2.z * wv.z + v2.w * wv.w;
        a3 += v3.x * wv.x + v3.y * wv.y + v3.z * wv.z + v3.w * wv.w;
      }
      red[h][0][tt] = a0; red[h][1][tt] = a1; red[h][2][tt] = a2; red[h][3][tt] = a3;
    }
    __syncthreads();
    if (h == 0) {
      float bb = bc2[tt];
#pragma unroll
      for (int p = 0; p < 4; ++p) {
        float v = red[0][p][tt] + red[1][p][tt] + bb;
        relf[(size_t)(p0 + p) * DD + tt] = v;
        sg[p][tt] = v;
      }
    }
    __syncthreads();
    // ---- P5: H_rel = relf @ Wg ----
    {
      const float4* w4 = (const float4*)(WgT + (size_t)tt * 256 + h * 128);
      const int hb = h * 128;
      float a0 = 0, a1 = 0, a2 = 0, a3 = 0;
#pragma unroll 8
      for (int j = 0; j < 32; ++j) {
        float4 wv = w4[j];
        float4 v0 = *(const float4*)&sg[0][hb + 4 * j];
        float4 v1 = *(const float4*)&sg[1][hb + 4 * j];
        float4 v2 = *(const float4*)&sg[2][hb + 4 * j];
        float4 v3 = *(const float4*)&sg[3][hb + 4 * j];
        a0 += v0.x * wv.x + v0.y * wv.y + v0.z * wv.z + v0.w * wv.w;
        a1 += v1.x * wv.x + v1.y * wv.y + v1.z * wv.z + v1.w * wv.w;
        a2 += v2.x * wv.x + v2.y * wv.y + v2.z * wv.z + v2.w * wv.w;
        a3 += v3.x * wv.x + v3.y * wv.y + v3.z * wv.z + v3.w * wv.w;
      }
      red[h][0][tt] = a0; red[h][1][tt] = a1; red[h][2][tt] = a2; red[h][3][tt] = a3;
    }
    __syncthreads();
    if (h == 0) {
#pragma unroll
      for (int p = 0; p < 4; ++p)
        H[(size_t)(NOBJ + p0 + p) * DD + tt] = red[0][p][tt] + red[1][p][tt];
    }
  } else {
    // ---- emb2 + H_obj ----
    const int r = (b - NP / 4) * 2 + h;   // 0..31
    float s[8];
#pragma unroll
    for (int u = 0; u < 8; ++u) s[u] = 0.f;
#pragma unroll
    for (int c0 = 0; c0 < CH; c0 += 8) {
#pragma unroll
      for (int u = 0; u < 8; ++u)
        s[u] += part[(size_t)(c0 + u) * (NOBJ * DD) + r * DD + tt];
    }
    float tot = ((s[0] + s[1]) + (s[2] + s[3])) + ((s[4] + s[5]) + (s[6] + s[7]));
    h2[h][tt] = fmaxf(tot + b1[tt], 0.f);
    __syncthreads();
    {
      const float4* w4 = (const float4*)(W2T + (size_t)tt * DD);
      const float* hp = &h2[h][0];
      float a0 = 0, a1 = 0, a2 = 0, a3 = 0;
#pragma unroll 8
      for (int j = 0; j < 64; ++j) {
        float4 wv = w4[j];
        float4 hv = *(const float4*)&hp[4 * j];
        a0 += hv.x * wv.x; a1 += hv.y * wv.y; a2 += hv.z * wv.z; a3 += hv.w * wv.w;
      }
      float v = (a0 + a1) + (a2 + a3) + b2[tt];
      objf[r * DD + tt] = v;
      sg[h][tt] = v;
    }
    __syncthreads();
    {
      const float4* w4 = (const float4*)(WgT + (size_t)tt * DD);
      const float* hp = &sg[h][0];
      float a0 = 0, a1 = 0, a2 = 0, a3 = 0;
#pragma unroll 8
      for (int j = 0; j < 64; ++j) {
        float4 wv = w4[j];
        float4 hv = *(const float4*)&hp[4 * j];
        a0 += hv.x * wv.x; a1 += hv.y * wv.y; a2 += hv.z * wv.z; a3 += hv.w * wv.w;
      }
      H[(size_t)r * DD + tt] = (a0 + a1) + (a2 + a3);
    }
  }
}

// ============ K_HEADS: rel(0..247, 4 pairs) + obj(248..279), 1024 thr ======
__global__ void __launch_bounds__(1024, 1)
k_heads(const float* __restrict__ H, const float* __restrict__ objf,
        const float* __restrict__ relf, const int* __restrict__ pairs,
        const float* __restrict__ bg,
        const float* __restrict__ WopT, const float* __restrict__ bop,
        const float* __restrict__ WrpT, const float* __restrict__ brp,
        float* __restrict__ out) {
  const int b = blockIdx.x, t = threadIdx.x;
  const int p = t >> 8, tt = t & 255;
  if (b < NP / 4) {
    __shared__ __align__(16) float gr[4][DD];
    __shared__ float red[4][4][64];
    const int r = b * 4 + p;
    int si = pairs[2 * r], oi = pairs[2 * r + 1];
    float hsum = H[si * DD + tt] + H[oi * DD + tt] + H[(size_t)(NOBJ + r) * DD + tt];
    gr[p][tt] = fmaxf(hsum * (1.f / 3.f) + bg[tt], 0.f) + relf[(size_t)r * DD + tt];
    __syncthreads();
    const int q = tt >> 6, c = tt & 63;
    float a = 0.f;
    if (c < RC) {
      const float4* w4 = (const float4*)(WrpT + c * 256 + q * 64);
#pragma unroll
      for (int j = 0; j < 16; ++j) {
        float4 wv = w4[j];
        float4 gv = *(const float4*)&gr[p][q * 64 + 4 * j];
        a += gv.x * wv.x + gv.y * wv.y + gv.z * wv.z + gv.w * wv.w;
      }
    }
    red[p][q][c] = a;
    __syncthreads();
    if (tt < RC)
      out[NOBJ * OC + (size_t)r * RC + tt] =
          red[p][0][tt] + red[p][1][tt] + red[p][2][tt] + red[p][3][tt] + brp[tt];
  } else {
    const int i = b - NP / 4;   // 0..31
    const int slice = p;
    __shared__ int2 pr[NP];
    __shared__ float red2[4][DD];
    __shared__ __align__(16) float gro[DD];
    const int2* p2 = (const int2*)pairs;
    for (int r = t; r < NP; r += 1024) pr[r] = p2[r];
    __syncthreads();
    float acc = 0.f;
    if (slice == 0) {
#pragma unroll 8
      for (int j = 0; j < NOBJ; ++j) acc += H[j * DD + tt];
    }
    const int rbeg = slice * 248;
#pragma unroll 8
    for (int r = rbeg; r < rbeg + 248; ++r) {
      int2 q = pr[r];
      float v = H[(size_t)(NOBJ + r) * DD + tt];
      if (q.x == i || q.y == i) acc += v;
    }
    red2[slice][tt] = acc;
    __syncthreads();
    if (t < DD) {
      float pre = (red2[0][t] + red2[1][t] + red2[2][t] + red2[3][t]) * (1.f / 94.f);
      gro[t] = fmaxf(pre + bg[t], 0.f) + objf[i * DD + t];
    }
    __syncthreads();
    float hsum = 0.f;
    if (tt < OC) {
      const float4* w4 = (const float4*)(WopT + tt * 256 + slice * 64);
#pragma unroll
      for (int j = 0; j < 16; ++j) {
        float4 wv = w4[j];
        float4 gv = *(const float4*)&gro[slice * 64 + 4 * j];
        hsum += gv.x * wv.x + gv.y * wv.y + gv.z * wv.z + gv.w * wv.w;
      }
    }
    red2[slice][tt] = hsum;
    __syncthreads();
    if (t < OC)
      out[i * OC + t] = red2[0][t] + red2[1][t] + red2[2][t] + red2[3][t] + bop[t];
  }
}

extern "C" void kernel_launch(void* const* d_in, const int* in_sizes, int n_in,
                              void* d_out, int out_size, void* d_ws, size_t ws_size,
                              hipStream_t stream) {
  const float* roi   = (const float*)d_in[0];
  const float* bbox  = (const float*)d_in[1];
  const float* logit = (const float*)d_in[2];
  const float* uf    = (const float*)d_in[3];
  const int*   pairs = (const int*)d_in[4];
  const float* W1    = (const float*)d_in[5];
  const float* b1    = (const float*)d_in[6];
  const float* W2    = (const float*)d_in[7];
  const float* b2    = (const float*)d_in[8];
  const float* fc1w  = (const float*)d_in[9];
  const float* fc1b  = (const float*)d_in[10];
  const float* fc2w  = (const float*)d_in[11];
  const float* fc2b  = (const float*)d_in[12];
  const float* Wc1   = (const float*)d_in[13];
  const float* bc1   = (const float*)d_in[14];
  const float* Wc2   = (const float*)d_in[15];
  const float* bc2   = (const float*)d_in[16];
  const float* Wg    = (const float*)d_in[17];
  const float* bg    = (const float*)d_in[18];
  const float* Wop   = (const float*)d_in[19];
  const float* bop   = (const float*)d_in[20];
  const float* Wrp   = (const float*)d_in[21];
  const float* brp   = (const float*)d_in[22];

  float* ws    = (float*)d_ws;
  float* part  = ws + OFF_PART;
  float* objf  = ws + OFF_OBJF;
  float* sAll  = ws + OFF_SALL;
  float* relf  = ws + OFF_RELF;
  float* Hbuf  = ws + OFF_H;
  float* W2T   = ws + OFF_W2T;
  float* Wc1T  = ws + OFF_WC1T;
  float* Wc2T  = ws + OFF_WC2T;
  float* WgT   = ws + OFF_WGT;
  float* f1wT  = ws + OFF_FC1WT;
  float* f2wT  = ws + OFF_FC2WT;
  float* WopT  = ws + OFF_WOPT;
  float* WrpT  = ws + OFF_WRPT;
  float* out   = (float*)d_out;

  k_pre<<<NP + CH + 256, 256, 0, stream>>>(uf, bbox, pairs, roi, logit, W1,
                                           W2, Wc1, Wc2, Wg, fc1w, fc2w, Wop, Wrp,
                                           sAll, part, W2T, Wc1T, Wc2T, WgT,
                                           f1wT, f2wT, WopT, WrpT);
  k_mid2<<<NP / 4 + 16, 512, 0, stream>>>(sAll, f1wT, fc1b, f2wT, fc2b,
                                          Wc1T, bc1, Wc2T, bc2, WgT,
                                          part, b1, W2T, b2, relf, objf, Hbuf);
  k_heads<<<NP / 4 + NOBJ, 1024, 0, stream>>>(Hbuf, objf, relf, pairs, bg,
                                              WopT, bop, WrpT, brp, out);
}